// Round 3
// baseline (390.914 us; speedup 1.0000x reference)
//
#include <hip/hip_runtime.h>

// Problem constants (from reference)
#define BATCH 2
#define HH 512
#define WW 512
#define NIN 64
#define NOUT 64
#define N_NZ 131072
#define N_MASK 131072
#define NPIX (BATCH * HH * WW)   // 524288
#define PPW 64                   // points per wave in conv kernel
#define MAX_ALIVE N_MASK         // alive pixels <= number of mask points

// d_ws layout (compact path).  slot placed AFTER compact so the single
// memset covers only {counter, mask, compact}; slot is fully overwritten by
// build_slot2 before any reader, so it needs no zeroing.
//   [0,256)            int counter
//   [256, +2MB)        float mask[NPIX]
//   [.., +32MB)        float compact[MAX_ALIVE*NOUT]
//   [.., +2MB)         int   slot[NPIX]     (NOT memset)
#define WS_MASK_OFF   256
#define WS_CMP_OFF    (WS_MASK_OFF + (size_t)NPIX * 4)
#define WS_SLOT_OFF   (WS_CMP_OFF + (size_t)MAX_ALIVE * NOUT * 4)
#define WS_NEED       (WS_SLOT_OFF + (size_t)NPIX * 4)
#define WS_MEMSET     WS_SLOT_OFF

// ---------------------------------------------------------------------------
// Mask scatter:  mask[b,y,x] += mask_values[n]
// ---------------------------------------------------------------------------
__global__ void mask_scatter_kernel(const float* __restrict__ mv,
                                    const int* __restrict__ midx,
                                    float* __restrict__ mask) {
    int n = blockIdx.x * blockDim.x + threadIdx.x;
    if (n < N_MASK) {
        int b = midx[n * 3 + 0];
        int y = midx[n * 3 + 1];
        int x = midx[n * 3 + 2];
        atomicAdd(&mask[(b * HH + y) * WW + x], mv[n]);
    }
}

// ---------------------------------------------------------------------------
// Slot assignment: block-aggregated scan, ONE counter atomic per block.
// ---------------------------------------------------------------------------
__global__ __launch_bounds__(256) void build_slot2_kernel(
        const float* __restrict__ mask,
        int* __restrict__ slot,
        int* __restrict__ counter) {
    const int tid = threadIdx.x;
    const int gid = blockIdx.x * 256 + tid;     // over NPIX/4 groups
    const float4 m = reinterpret_cast<const float4*>(mask)[gid];
    const int c0 = (m.x != 0.f) + (m.y != 0.f) + (m.z != 0.f) + (m.w != 0.f);

    const int lane = tid & 63;
    const int wv = tid >> 6;
    int pre = c0;
#pragma unroll
    for (int d = 1; d < 64; d <<= 1) {
        int t = __shfl_up(pre, d);
        if (lane >= d) pre += t;
    }

    __shared__ int wsum[4];
    __shared__ int wbase[4];
    __shared__ int blockbase;
    if (lane == 63) wsum[wv] = pre;
    __syncthreads();
    if (tid == 0) {
        int s = 0;
#pragma unroll
        for (int w = 0; w < 4; ++w) { wbase[w] = s; s += wsum[w]; }
        blockbase = atomicAdd(counter, s);      // ONE atomic per block
    }
    __syncthreads();

    int s0 = blockbase + wbase[wv] + (pre - c0);  // exclusive prefix
    int4 sv;
    sv.x = (m.x != 0.f) ? s0++ : -1;
    sv.y = (m.y != 0.f) ? s0++ : -1;
    sv.z = (m.z != 0.f) ? s0++ : -1;
    sv.w = (m.w != 0.f) ? s0++ : -1;
    reinterpret_cast<int4*>(slot)[gid] = sv;
}

// ---------------------------------------------------------------------------
// Conv scatter v5 (R7, resubmitted R8 unchanged — no bench data yet):
// register-pinned kernel slice + 4-DEEP pipeline.
//   * 4 waves / 256-thread block (wave = one (tile,tap)): escapes the
//     16-workgroup/CU cap, cuts dispatch count 4x, keeps 4 taps of one tile
//     on the same CU so the uniform values-row s_loads stay cache-hot.
//   * Alive loop: FOUR points per iteration with independent accumulator
//     chains.  4 interleaved fmac chains fully cover the ~4cy dep latency
//     and the 4 rows' scalar loads share one ~200cy L2 latency window.
//   All wave ops stay wave-uniform; no __syncthreads; multi-wave safe.
// ---------------------------------------------------------------------------
__global__ __launch_bounds__(256, 2) void conv_scatter5_kernel(
        const float* __restrict__ values,   // (N_NZ, NIN)
        const float* __restrict__ kern,     // (3,3,NIN,NOUT)
        const int* __restrict__ idx,        // (N_NZ,3) int32
        const int* __restrict__ slot,       // (NPIX,) slot id or -1
        float* __restrict__ compact) {      // (MAX_ALIVE, NOUT) zeroed
    const int wv   = threadIdx.x >> 6;              // wave in block
    const int wg   = blockIdx.x * 4 + wv;           // global wave id
    const int tap  = wg % 9;                        // 9 taps of a tile adjacent
    const int tile = wg / 9;                        // -> values rows cache-hot
    const int lane = threadIdx.x & 63;
    const int ky = tap / 3;
    const int kx = tap % 3;

    // This tap's 64x64 kernel slice -> 64 VGPRs (lane = output channel).
    float kreg[NIN];
    const float* kp = kern + (size_t)tap * NIN * NOUT + lane;
#pragma unroll
    for (int i = 0; i < NIN; ++i) kreg[i] = kp[(size_t)i * NOUT];
    // Pin: forbid rematerialization (R5 evidence: VGPR_Count=36 remat bug).
#pragma unroll
    for (int i = 0; i < NIN; ++i) asm volatile("" : "+v"(kreg[i]));

    // Lane-parallel probe of 64 points' destinations.
    const int p0 = tile * PPW;
    const int p  = p0 + lane;
    const int b = idx[p * 3 + 0];
    const int y = idx[p * 3 + 1];
    const int x = idx[p * 3 + 2];
    const int sy = min(max(y + ky - 1, 0), HH - 1);
    const int sx = min(max(x + kx - 1, 0), WW - 1);
    const int pix = (b * HH + sy) * WW + sx;
    const int s = slot[pix];

    unsigned long long alive = __ballot(s >= 0);

    // 4-deep: four independent accumulator chains per iteration.
    while (__popcll(alive) >= 4) {
        const int j0 = __ffsll((long long)alive) - 1; alive &= alive - 1;
        const int j1 = __ffsll((long long)alive) - 1; alive &= alive - 1;
        const int j2 = __ffsll((long long)alive) - 1; alive &= alive - 1;
        const int j3 = __ffsll((long long)alive) - 1; alive &= alive - 1;
        const int sj0 = __shfl(s, j0);
        const int sj1 = __shfl(s, j1);
        const int sj2 = __shfl(s, j2);
        const int sj3 = __shfl(s, j3);
        const float* vp0 = values + (size_t)(p0 + j0) * NIN;  // uniform->s_load
        const float* vp1 = values + (size_t)(p0 + j1) * NIN;
        const float* vp2 = values + (size_t)(p0 + j2) * NIN;
        const float* vp3 = values + (size_t)(p0 + j3) * NIN;
        float a0 = 0.f, a1 = 0.f, a2 = 0.f, a3 = 0.f;
#pragma unroll
        for (int i = 0; i < NIN; ++i) {
            a0 = fmaf(vp0[i], kreg[i], a0);
            a1 = fmaf(vp1[i], kreg[i], a1);
            a2 = fmaf(vp2[i], kreg[i], a2);
            a3 = fmaf(vp3[i], kreg[i], a3);
        }
        atomicAdd(&compact[(size_t)sj0 * NOUT + lane], a0);
        atomicAdd(&compact[(size_t)sj1 * NOUT + lane], a1);
        atomicAdd(&compact[(size_t)sj2 * NOUT + lane], a2);
        atomicAdd(&compact[(size_t)sj3 * NOUT + lane], a3);
    }
    // Remainder (<=3 points).
    while (alive) {
        const int j0 = __ffsll((long long)alive) - 1; alive &= alive - 1;
        const int sj0 = __shfl(s, j0);
        const float* vp0 = values + (size_t)(p0 + j0) * NIN;
        float a0 = 0.f;
#pragma unroll
        for (int i = 0; i < NIN; ++i) a0 = fmaf(vp0[i], kreg[i], a0);
        atomicAdd(&compact[(size_t)sj0 * NOUT + lane], a0);
    }
}

// ---------------------------------------------------------------------------
// Streaming finalize: writes EVERY output element exactly once.
//   dead pixel  -> 0 ; alive -> (compact[slot] + m*bias) * m
// ---------------------------------------------------------------------------
__global__ void finalize2_kernel(float* __restrict__ out,
                                 const float* __restrict__ mask,
                                 const int* __restrict__ slot,
                                 const float* __restrict__ compact,
                                 const float* __restrict__ bias) {
    const int t = blockIdx.x * blockDim.x + threadIdx.x;
    const int p = t >> 4;
    const int c4 = (t & 15) * 4;
    if (p >= NPIX) return;
    float4* o = reinterpret_cast<float4*>(out + (size_t)p * NOUT + c4);
    const int s = slot[p];
    if (s < 0) {
        *o = make_float4(0.f, 0.f, 0.f, 0.f);
        return;
    }
    const float m = mask[p];
    const float4 bb = *reinterpret_cast<const float4*>(bias + c4);
    float4 v = *reinterpret_cast<const float4*>(compact + (size_t)s * NOUT + c4);
    v.x = (v.x + m * bb.x) * m;
    v.y = (v.y + m * bb.y) * m;
    v.z = (v.z + m * bb.z) * m;
    v.w = (v.w + m * bb.w) * m;
    *o = v;
}

// ======================= Fallback path (R3, proven) ========================
__global__ __launch_bounds__(64, 2) void conv_scatter_kernel(
        const float* __restrict__ values,
        const float* __restrict__ kern,
        const int* __restrict__ idx,
        const float* __restrict__ mask,
        float* __restrict__ dense) {
    const int bid  = blockIdx.x;
    const int tap  = bid % 9;
    const int tile = bid / 9;
    const int lane = threadIdx.x;
    const int ky = tap / 3;
    const int kx = tap % 3;
    float kreg[NIN];
    const float* kp = kern + (size_t)tap * NIN * NOUT + lane;
#pragma unroll
    for (int i = 0; i < NIN; ++i) kreg[i] = kp[(size_t)i * NOUT];
#pragma unroll
    for (int i = 0; i < NIN; ++i) asm volatile("" : "+v"(kreg[i]));
    const int p0 = tile * PPW;
    for (int pp = 0; pp < PPW; ++pp) {
        const int p = p0 + pp;
        const int b = idx[p * 3 + 0];
        const int y = idx[p * 3 + 1];
        const int x = idx[p * 3 + 2];
        const int sy = min(max(y + ky - 1, 0), HH - 1);
        const int sx = min(max(x + kx - 1, 0), WW - 1);
        const size_t pix = ((size_t)b * HH + sy) * WW + sx;
        if (mask[pix] != 0.0f) {
            const float* vp = values + (size_t)p * NIN;
            float acc = 0.0f;
#pragma unroll
            for (int i = 0; i < NIN; ++i) acc = fmaf(vp[i], kreg[i], acc);
            atomicAdd(&dense[pix * NOUT + lane], acc);
        }
    }
}

__global__ void finalize_kernel(float* __restrict__ out,
                                const float* __restrict__ mask,
                                const float* __restrict__ bias) {
    const int t = blockIdx.x * blockDim.x + threadIdx.x;
    const int p = t >> 4;
    const int c4 = (t & 15) * 4;
    if (p >= NPIX) return;
    const float m = mask[p];
    if (m == 0.0f) return;
    float4* o = reinterpret_cast<float4*>(out + (size_t)p * NOUT + c4);
    const float4 bb = *reinterpret_cast<const float4*>(bias + c4);
    float4 v = *o;
    v.x = (v.x + m * bb.x) * m;
    v.y = (v.y + m * bb.y) * m;
    v.z = (v.z + m * bb.z) * m;
    v.w = (v.w + m * bb.w) * m;
    *o = v;
}

extern "C" void kernel_launch(void* const* d_in, const int* in_sizes, int n_in,
                              void* d_out, int out_size, void* d_ws, size_t ws_size,
                              hipStream_t stream) {
    const float* values      = (const float*)d_in[0];
    const float* kern        = (const float*)d_in[1];
    const float* bias        = (const float*)d_in[2];
    const float* mask_values = (const float*)d_in[3];
    const int*   indices     = (const int*)d_in[4];
    const int*   mask_idx    = (const int*)d_in[5];
    float* out = (float*)d_out;

    if (ws_size >= WS_NEED) {
        // ---- compact path ----
        char* ws = (char*)d_ws;
        int*   counter = (int*)ws;
        float* mask    = (float*)(ws + WS_MASK_OFF);
        float* compact = (float*)(ws + WS_CMP_OFF);
        int*   slot    = (int*)(ws + WS_SLOT_OFF);

        hipMemsetAsync(ws, 0, WS_MEMSET, stream);  // counter+mask+compact

        mask_scatter_kernel<<<(N_MASK + 255) / 256, 256, 0, stream>>>(
            mask_values, mask_idx, mask);
        build_slot2_kernel<<<NPIX / 4 / 256, 256, 0, stream>>>(
            mask, slot, counter);

        const int nwaves = 9 * (N_NZ / PPW);        // 18432
        conv_scatter5_kernel<<<nwaves / 4, 256, 0, stream>>>(
            values, kern, indices, slot, compact);

        const int total = NPIX * (NOUT / 4);
        finalize2_kernel<<<(total + 255) / 256, 256, 0, stream>>>(
            out, mask, slot, compact, bias);
    } else {
        // ---- fallback: R3 structure ----
        float* mask = (float*)d_ws;
        hipMemsetAsync(out, 0, (size_t)out_size * sizeof(float), stream);
        hipMemsetAsync(mask, 0, (size_t)NPIX * sizeof(float), stream);
        mask_scatter_kernel<<<(N_MASK + 255) / 256, 256, 0, stream>>>(
            mask_values, mask_idx, mask);
        const int nblocks = 9 * (N_NZ / PPW);
        conv_scatter_kernel<<<nblocks, 64, 0, stream>>>(
            values, kern, indices, mask, out);
        const int total = NPIX * (NOUT / 4);
        finalize_kernel<<<(total + 255) / 256, 256, 0, stream>>>(out, mask, bias);
    }
}

// Round 6
// 253.326 us; speedup vs baseline: 1.5431x; 1.5431x over previous
//
#include <hip/hip_runtime.h>

// Problem constants (from reference)
#define BATCH 2
#define HH 512
#define WW 512
#define NIN 64
#define NOUT 64
#define N_NZ 131072
#define N_MASK 131072
#define NPIX (BATCH * HH * WW)   // 524288
#define PPW 64                   // points per wave in conv kernel
#define MAX_ALIVE N_MASK         // alive pixels <= number of mask points

// d_ws layout (compact path).  slot placed AFTER compact so the single
// memset covers only {counter, mask, compact}; slot is fully overwritten by
// build_slot2 before any reader, so it needs no zeroing.
//   [0,256)            int counter
//   [256, +2MB)        float mask[NPIX]
//   [.., +32MB)        float compact[MAX_ALIVE*NOUT]
//   [.., +2MB)         int   slot[NPIX]     (NOT memset)
#define WS_MASK_OFF   256
#define WS_CMP_OFF    (WS_MASK_OFF + (size_t)NPIX * 4)
#define WS_SLOT_OFF   (WS_CMP_OFF + (size_t)MAX_ALIVE * NOUT * 4)
#define WS_NEED       (WS_SLOT_OFF + (size_t)NPIX * 4)
#define WS_MEMSET     WS_SLOT_OFF

// ---------------------------------------------------------------------------
// Mask scatter:  mask[b,y,x] += mask_values[n]
// ---------------------------------------------------------------------------
__global__ void mask_scatter_kernel(const float* __restrict__ mv,
                                    const int* __restrict__ midx,
                                    float* __restrict__ mask) {
    int n = blockIdx.x * blockDim.x + threadIdx.x;
    if (n < N_MASK) {
        int b = midx[n * 3 + 0];
        int y = midx[n * 3 + 1];
        int x = midx[n * 3 + 2];
        atomicAdd(&mask[(b * HH + y) * WW + x], mv[n]);
    }
}

// ---------------------------------------------------------------------------
// Slot assignment: block-aggregated scan, ONE counter atomic per block.
// ---------------------------------------------------------------------------
__global__ __launch_bounds__(256) void build_slot2_kernel(
        const float* __restrict__ mask,
        int* __restrict__ slot,
        int* __restrict__ counter) {
    const int tid = threadIdx.x;
    const int gid = blockIdx.x * 256 + tid;     // over NPIX/4 groups
    const float4 m = reinterpret_cast<const float4*>(mask)[gid];
    const int c0 = (m.x != 0.f) + (m.y != 0.f) + (m.z != 0.f) + (m.w != 0.f);

    const int lane = tid & 63;
    const int wv = tid >> 6;
    int pre = c0;
#pragma unroll
    for (int d = 1; d < 64; d <<= 1) {
        int t = __shfl_up(pre, d);
        if (lane >= d) pre += t;
    }

    __shared__ int wsum[4];
    __shared__ int wbase[4];
    __shared__ int blockbase;
    if (lane == 63) wsum[wv] = pre;
    __syncthreads();
    if (tid == 0) {
        int s = 0;
#pragma unroll
        for (int w = 0; w < 4; ++w) { wbase[w] = s; s += wsum[w]; }
        blockbase = atomicAdd(counter, s);      // ONE atomic per block
    }
    __syncthreads();

    int s0 = blockbase + wbase[wv] + (pre - c0);  // exclusive prefix
    int4 sv;
    sv.x = (m.x != 0.f) ? s0++ : -1;
    sv.y = (m.y != 0.f) ? s0++ : -1;
    sv.z = (m.z != 0.f) ? s0++ : -1;
    sv.w = (m.w != 0.f) ? s0++ : -1;
    reinterpret_cast<int4*>(slot)[gid] = sv;
}

// ---------------------------------------------------------------------------
// Conv scatter v6 (R9; resubmitted R10/R11 — GPU never acquired, no data):
// VECTOR-path row loads via LDS broadcast.
// R8 evidence: conv5 at 220us with VALUBusy 14.8%, HBM 6%, banks 0,
// occupancy 35% -> waves stalled on the SCALAR memory pipe (uniform row
// pointers compile to s_load; SQC has no deep MLP queue).  v6 loads each
// row COALESCED on the vector path (lane i loads element i, one 256B
// request), stages it in wave-private LDS, and reads it back with
// broadcast ds_read_b128 (uniform addr, conflict-free).  Next group's 4
// row loads are issued BEFORE the current group's 256 fmacs, hiding L2
// latency under compute.  Atomics deliberately untouched: if conv stays
// ~200us, the atomic write-through path is the wall (pivot next).
// ---------------------------------------------------------------------------
__global__ __launch_bounds__(256, 2) void conv_scatter6_kernel(
        const float* __restrict__ values,   // (N_NZ, NIN)
        const float* __restrict__ kern,     // (3,3,NIN,NOUT)
        const int* __restrict__ idx,        // (N_NZ,3) int32
        const int* __restrict__ slot,       // (NPIX,) slot id or -1
        float* __restrict__ compact) {      // (MAX_ALIVE, NOUT) zeroed
    const int wv   = threadIdx.x >> 6;              // wave in block
    const int wg   = blockIdx.x * 4 + wv;           // global wave id
    const int tap  = wg % 9;                        // 9 taps of a tile adjacent
    const int tile = wg / 9;                        // -> values rows L2-hot
    const int lane = threadIdx.x & 63;
    const int ky = tap / 3;
    const int kx = tap % 3;

    // Wave-private row staging: [wave][parity][chain][elem] = 8KB/block.
    __shared__ __align__(16) float rows[4][2][4][NIN];

    // This tap's 64x64 kernel slice -> 64 regs (lane = output channel).
    float kreg[NIN];
    const float* kp = kern + (size_t)tap * NIN * NOUT + lane;
#pragma unroll
    for (int i = 0; i < NIN; ++i) kreg[i] = kp[(size_t)i * NOUT];
    // Pin: forbid rematerialization (R5 evidence: remat re-read 16KB/wave).
#pragma unroll
    for (int i = 0; i < NIN; ++i) asm volatile("" : "+v"(kreg[i]));

    // Lane-parallel probe of 64 points' destinations.
    const int p0 = tile * PPW;
    const int p  = p0 + lane;
    const int b = idx[p * 3 + 0];
    const int y = idx[p * 3 + 1];
    const int x = idx[p * 3 + 2];
    const int sy = min(max(y + ky - 1, 0), HH - 1);
    const int sx = min(max(x + kx - 1, 0), WW - 1);
    const int pix = (b * HH + sy) * WW + sx;
    const int s = slot[pix];

    unsigned long long mrem = __ballot(s >= 0);
    int cnt = __popcll(mrem);                       // uniform

    int J0 = 0, J1 = 0, J2 = 0, J3 = 0;
    float c0 = 0.f, c1 = 0.f, c2 = 0.f, c3 = 0.f;
    if (cnt >= 4) {                                 // prologue: prefetch g1
        J0 = __ffsll((long long)mrem) - 1; mrem &= mrem - 1;
        J1 = __ffsll((long long)mrem) - 1; mrem &= mrem - 1;
        J2 = __ffsll((long long)mrem) - 1; mrem &= mrem - 1;
        J3 = __ffsll((long long)mrem) - 1; mrem &= mrem - 1;
        c0 = values[(size_t)(p0 + J0) * NIN + lane];   // coalesced 256B
        c1 = values[(size_t)(p0 + J1) * NIN + lane];
        c2 = values[(size_t)(p0 + J2) * NIN + lane];
        c3 = values[(size_t)(p0 + J3) * NIN + lane];
    }
    int pc = 0;
    while (cnt >= 4) {
        cnt -= 4;
        // Current group's slots (J* captured before the prefetch pops).
        const int s0 = __shfl(s, J0);
        const int s1 = __shfl(s, J1);
        const int s2 = __shfl(s, J2);
        const int s3 = __shfl(s, J3);
        // Stage current rows to LDS (waits vmcnt for the loads).
        float* rw = &rows[wv][pc][0][0];
        rw[0 * NIN + lane] = c0;
        rw[1 * NIN + lane] = c1;
        rw[2 * NIN + lane] = c2;
        rw[3 * NIN + lane] = c3;
        // Prefetch next group's rows (latency hides under fmacs below).
        float n0 = 0.f, n1 = 0.f, n2 = 0.f, n3 = 0.f;
        if (cnt >= 4) {
            J0 = __ffsll((long long)mrem) - 1; mrem &= mrem - 1;
            J1 = __ffsll((long long)mrem) - 1; mrem &= mrem - 1;
            J2 = __ffsll((long long)mrem) - 1; mrem &= mrem - 1;
            J3 = __ffsll((long long)mrem) - 1; mrem &= mrem - 1;
            n0 = values[(size_t)(p0 + J0) * NIN + lane];
            n1 = values[(size_t)(p0 + J1) * NIN + lane];
            n2 = values[(size_t)(p0 + J2) * NIN + lane];
            n3 = values[(size_t)(p0 + J3) * NIN + lane];
        }
        // Broadcast ds_read_b128 (uniform addr, conflict-free) + 4 chains.
        const float4* q0 = reinterpret_cast<const float4*>(rw + 0 * NIN);
        const float4* q1 = reinterpret_cast<const float4*>(rw + 1 * NIN);
        const float4* q2 = reinterpret_cast<const float4*>(rw + 2 * NIN);
        const float4* q3 = reinterpret_cast<const float4*>(rw + 3 * NIN);
        float a0 = 0.f, a1 = 0.f, a2 = 0.f, a3 = 0.f;
#pragma unroll
        for (int i4 = 0; i4 < 16; ++i4) {
            const float4 w0 = q0[i4];
            const float4 w1 = q1[i4];
            const float4 w2 = q2[i4];
            const float4 w3 = q3[i4];
            a0 = fmaf(w0.x, kreg[4 * i4 + 0], a0);
            a0 = fmaf(w0.y, kreg[4 * i4 + 1], a0);
            a0 = fmaf(w0.z, kreg[4 * i4 + 2], a0);
            a0 = fmaf(w0.w, kreg[4 * i4 + 3], a0);
            a1 = fmaf(w1.x, kreg[4 * i4 + 0], a1);
            a1 = fmaf(w1.y, kreg[4 * i4 + 1], a1);
            a1 = fmaf(w1.z, kreg[4 * i4 + 2], a1);
            a1 = fmaf(w1.w, kreg[4 * i4 + 3], a1);
            a2 = fmaf(w2.x, kreg[4 * i4 + 0], a2);
            a2 = fmaf(w2.y, kreg[4 * i4 + 1], a2);
            a2 = fmaf(w2.z, kreg[4 * i4 + 2], a2);
            a2 = fmaf(w2.w, kreg[4 * i4 + 3], a2);
            a3 = fmaf(w3.x, kreg[4 * i4 + 0], a3);
            a3 = fmaf(w3.y, kreg[4 * i4 + 1], a3);
            a3 = fmaf(w3.z, kreg[4 * i4 + 2], a3);
            a3 = fmaf(w3.w, kreg[4 * i4 + 3], a3);
        }
        atomicAdd(&compact[(size_t)s0 * NOUT + lane], a0);
        atomicAdd(&compact[(size_t)s1 * NOUT + lane], a1);
        atomicAdd(&compact[(size_t)s2 * NOUT + lane], a2);
        atomicAdd(&compact[(size_t)s3 * NOUT + lane], a3);
        c0 = n0; c1 = n1; c2 = n2; c3 = n3;     // rotate prefetched rows
        pc ^= 1;
    }
    // Remainder (<=3 dots): simple path.
    while (mrem) {
        const int j = __ffsll((long long)mrem) - 1; mrem &= mrem - 1;
        const int sj = __shfl(s, j);
        const float* vp = values + (size_t)(p0 + j) * NIN;
        float a = 0.f;
#pragma unroll
        for (int i = 0; i < NIN; ++i) a = fmaf(vp[i], kreg[i], a);
        atomicAdd(&compact[(size_t)sj * NOUT + lane], a);
    }
}

// ---------------------------------------------------------------------------
// Streaming finalize: writes EVERY output element exactly once.
//   dead pixel  -> 0 ; alive -> (compact[slot] + m*bias) * m
// ---------------------------------------------------------------------------
__global__ void finalize2_kernel(float* __restrict__ out,
                                 const float* __restrict__ mask,
                                 const int* __restrict__ slot,
                                 const float* __restrict__ compact,
                                 const float* __restrict__ bias) {
    const int t = blockIdx.x * blockDim.x + threadIdx.x;
    const int p = t >> 4;
    const int c4 = (t & 15) * 4;
    if (p >= NPIX) return;
    float4* o = reinterpret_cast<float4*>(out + (size_t)p * NOUT + c4);
    const int s = slot[p];
    if (s < 0) {
        *o = make_float4(0.f, 0.f, 0.f, 0.f);
        return;
    }
    const float m = mask[p];
    const float4 bb = *reinterpret_cast<const float4*>(bias + c4);
    float4 v = *reinterpret_cast<const float4*>(compact + (size_t)s * NOUT + c4);
    v.x = (v.x + m * bb.x) * m;
    v.y = (v.y + m * bb.y) * m;
    v.z = (v.z + m * bb.z) * m;
    v.w = (v.w + m * bb.w) * m;
    *o = v;
}

// ======================= Fallback path (R3, proven) ========================
__global__ __launch_bounds__(64, 2) void conv_scatter_kernel(
        const float* __restrict__ values,
        const float* __restrict__ kern,
        const int* __restrict__ idx,
        const float* __restrict__ mask,
        float* __restrict__ dense) {
    const int bid  = blockIdx.x;
    const int tap  = bid % 9;
    const int tile = bid / 9;
    const int lane = threadIdx.x;
    const int ky = tap / 3;
    const int kx = tap % 3;
    float kreg[NIN];
    const float* kp = kern + (size_t)tap * NIN * NOUT + lane;
#pragma unroll
    for (int i = 0; i < NIN; ++i) kreg[i] = kp[(size_t)i * NOUT];
#pragma unroll
    for (int i = 0; i < NIN; ++i) asm volatile("" : "+v"(kreg[i]));
    const int p0 = tile * PPW;
    for (int pp = 0; pp < PPW; ++pp) {
        const int p = p0 + pp;
        const int b = idx[p * 3 + 0];
        const int y = idx[p * 3 + 1];
        const int x = idx[p * 3 + 2];
        const int sy = min(max(y + ky - 1, 0), HH - 1);
        const int sx = min(max(x + kx - 1, 0), WW - 1);
        const size_t pix = ((size_t)b * HH + sy) * WW + sx;
        if (mask[pix] != 0.0f) {
            const float* vp = values + (size_t)p * NIN;
            float acc = 0.0f;
#pragma unroll
            for (int i = 0; i < NIN; ++i) acc = fmaf(vp[i], kreg[i], acc);
            atomicAdd(&dense[pix * NOUT + lane], acc);
        }
    }
}

__global__ void finalize_kernel(float* __restrict__ out,
                                const float* __restrict__ mask,
                                const float* __restrict__ bias) {
    const int t = blockIdx.x * blockDim.x + threadIdx.x;
    const int p = t >> 4;
    const int c4 = (t & 15) * 4;
    if (p >= NPIX) return;
    const float m = mask[p];
    if (m == 0.0f) return;
    float4* o = reinterpret_cast<float4*>(out + (size_t)p * NOUT + c4);
    const float4 bb = *reinterpret_cast<const float4*>(bias + c4);
    float4 v = *o;
    v.x = (v.x + m * bb.x) * m;
    v.y = (v.y + m * bb.y) * m;
    v.z = (v.z + m * bb.z) * m;
    v.w = (v.w + m * bb.w) * m;
    *o = v;
}

extern "C" void kernel_launch(void* const* d_in, const int* in_sizes, int n_in,
                              void* d_out, int out_size, void* d_ws, size_t ws_size,
                              hipStream_t stream) {
    const float* values      = (const float*)d_in[0];
    const float* kern        = (const float*)d_in[1];
    const float* bias        = (const float*)d_in[2];
    const float* mask_values = (const float*)d_in[3];
    const int*   indices     = (const int*)d_in[4];
    const int*   mask_idx    = (const int*)d_in[5];
    float* out = (float*)d_out;

    if (ws_size >= WS_NEED) {
        // ---- compact path ----
        char* ws = (char*)d_ws;
        int*   counter = (int*)ws;
        float* mask    = (float*)(ws + WS_MASK_OFF);
        float* compact = (float*)(ws + WS_CMP_OFF);
        int*   slot    = (int*)(ws + WS_SLOT_OFF);

        hipMemsetAsync(ws, 0, WS_MEMSET, stream);  // counter+mask+compact

        mask_scatter_kernel<<<(N_MASK + 255) / 256, 256, 0, stream>>>(
            mask_values, mask_idx, mask);
        build_slot2_kernel<<<NPIX / 4 / 256, 256, 0, stream>>>(
            mask, slot, counter);

        const int nwaves = 9 * (N_NZ / PPW);        // 18432
        conv_scatter6_kernel<<<nwaves / 4, 256, 0, stream>>>(
            values, kern, indices, slot, compact);

        const int total = NPIX * (NOUT / 4);
        finalize2_kernel<<<(total + 255) / 256, 256, 0, stream>>>(
            out, mask, slot, compact, bias);
    } else {
        // ---- fallback: R3 structure ----
        float* mask = (float*)d_ws;
        hipMemsetAsync(out, 0, (size_t)out_size * sizeof(float), stream);
        hipMemsetAsync(mask, 0, (size_t)NPIX * sizeof(float), stream);
        mask_scatter_kernel<<<(N_MASK + 255) / 256, 256, 0, stream>>>(
            mask_values, mask_idx, mask);
        const int nblocks = 9 * (N_NZ / PPW);
        conv_scatter_kernel<<<nblocks, 64, 0, stream>>>(
            values, kern, indices, mask, out);
        const int total = NPIX * (NOUT / 4);
        finalize_kernel<<<(total + 255) / 256, 256, 0, stream>>>(out, mask, bias);
    }
}

// Round 7
// 251.824 us; speedup vs baseline: 1.5523x; 1.0060x over previous
//
#include <hip/hip_runtime.h>

// Problem constants (from reference)
#define BATCH 2
#define HH 512
#define WW 512
#define NIN 64
#define NOUT 64
#define N_NZ 131072
#define N_MASK 131072
#define NPIX (BATCH * HH * WW)   // 524288
#define PPW 64                   // points per wave in conv kernel
#define MAX_ALIVE N_MASK         // alive pixels <= number of mask points

// d_ws layout (compact path).
//   [0,256)            int counter
//   [256, +2MB)        float mask[NPIX]
//   [.., +32MB)        float compact[MAX_ALIVE*NOUT]
//   [.., +2MB)         int   slot[NPIX]     (NOT memset)
#define WS_MASK_OFF   256
#define WS_CMP_OFF    (WS_MASK_OFF + (size_t)NPIX * 4)
#define WS_SLOT_OFF   (WS_CMP_OFF + (size_t)MAX_ALIVE * NOUT * 4)
#define WS_NEED       (WS_SLOT_OFF + (size_t)NPIX * 4)
#define WS_MEMSET     WS_SLOT_OFF

// ---------------------------------------------------------------------------
// Mask scatter:  mask[b,y,x] += mask_values[n]
// ---------------------------------------------------------------------------
__global__ void mask_scatter_kernel(const float* __restrict__ mv,
                                    const int* __restrict__ midx,
                                    float* __restrict__ mask) {
    int n = blockIdx.x * blockDim.x + threadIdx.x;
    if (n < N_MASK) {
        int b = midx[n * 3 + 0];
        int y = midx[n * 3 + 1];
        int x = midx[n * 3 + 2];
        atomicAdd(&mask[(b * HH + y) * WW + x], mv[n]);
    }
}

// ---------------------------------------------------------------------------
// Slot assignment: block-aggregated scan, ONE counter atomic per block.
// ---------------------------------------------------------------------------
__global__ __launch_bounds__(256) void build_slot2_kernel(
        const float* __restrict__ mask,
        int* __restrict__ slot,
        int* __restrict__ counter) {
    const int tid = threadIdx.x;
    const int gid = blockIdx.x * 256 + tid;     // over NPIX/4 groups
    const float4 m = reinterpret_cast<const float4*>(mask)[gid];
    const int c0 = (m.x != 0.f) + (m.y != 0.f) + (m.z != 0.f) + (m.w != 0.f);

    const int lane = tid & 63;
    const int wv = tid >> 6;
    int pre = c0;
#pragma unroll
    for (int d = 1; d < 64; d <<= 1) {
        int t = __shfl_up(pre, d);
        if (lane >= d) pre += t;
    }

    __shared__ int wsum[4];
    __shared__ int wbase[4];
    __shared__ int blockbase;
    if (lane == 63) wsum[wv] = pre;
    __syncthreads();
    if (tid == 0) {
        int s = 0;
#pragma unroll
        for (int w = 0; w < 4; ++w) { wbase[w] = s; s += wsum[w]; }
        blockbase = atomicAdd(counter, s);      // ONE atomic per block
    }
    __syncthreads();

    int s0 = blockbase + wbase[wv] + (pre - c0);  // exclusive prefix
    int4 sv;
    sv.x = (m.x != 0.f) ? s0++ : -1;
    sv.y = (m.y != 0.f) ? s0++ : -1;
    sv.z = (m.z != 0.f) ? s0++ : -1;
    sv.w = (m.w != 0.f) ? s0++ : -1;
    reinterpret_cast<int4*>(slot)[gid] = sv;
}

// ---------------------------------------------------------------------------
// Conv scatter v7 (R12): HYBRID row sourcing — LDS(48 els) + SCALAR(16 els).
// R11 evidence: conv6 = 80us, VALUBusy 41%, banks 0 -> 192 cyc/dot = 17 LDS
// instrs x ~11.3 cyc: LDS-instruction-issue-bound (uniform ds_read_b128
// gets no broadcast discount).  Each lane needs all 64 row elements; the
// LDS port moves 16B/instr -> 16 reads/dot irreducible on LDS alone.
// v7 routes els 48..63 through the SCALAR pipe: s_load_dwordx16 from a
// readfirstlane'd uniform row pointer, SGPR operands feed v_fmac directly.
// v5 calibration: scalar sustains ~1 cache line (16 els) per ~132 cyc --
// concurrent with LDS (~135 cyc for 12 reads+write) and VALU (128 cyc).
// Predicted bound ~145 cyc/dot (was 192).
// ---------------------------------------------------------------------------
__global__ __launch_bounds__(256, 4) void conv_scatter7_kernel(
        const float* __restrict__ values,   // (N_NZ, NIN)
        const float* __restrict__ kern,     // (3,3,NIN,NOUT)
        const int* __restrict__ idx,        // (N_NZ,3) int32
        const int* __restrict__ slot,       // (NPIX,) slot id or -1
        float* __restrict__ compact) {      // (MAX_ALIVE, NOUT) zeroed
    const int wv   = threadIdx.x >> 6;              // wave in block
    const int wg   = blockIdx.x * 4 + wv;           // global wave id
    const int tap  = wg % 9;                        // 9 taps of a tile adjacent
    const int tile = wg / 9;                        // -> values rows L2-hot
    const int lane = threadIdx.x & 63;
    const int ky = tap / 3;
    const int kx = tap % 3;

    // Wave-private row staging: [wave][parity][chain][elem] = 8KB/block.
    __shared__ __align__(16) float rows[4][2][4][NIN];

    // This tap's 64x64 kernel slice -> 64 regs (lane = output channel).
    float kreg[NIN];
    const float* kp = kern + (size_t)tap * NIN * NOUT + lane;
#pragma unroll
    for (int i = 0; i < NIN; ++i) kreg[i] = kp[(size_t)i * NOUT];
    // Pin: forbid rematerialization (R5 evidence: remat re-read 16KB/wave).
#pragma unroll
    for (int i = 0; i < NIN; ++i) asm volatile("" : "+v"(kreg[i]));

    // Lane-parallel probe of 64 points' destinations.
    const int p0 = tile * PPW;
    const int p  = p0 + lane;
    const int b = idx[p * 3 + 0];
    const int y = idx[p * 3 + 1];
    const int x = idx[p * 3 + 2];
    const int sy = min(max(y + ky - 1, 0), HH - 1);
    const int sx = min(max(x + kx - 1, 0), WW - 1);
    const int pix = (b * HH + sy) * WW + sx;
    const int s = slot[pix];

    unsigned long long mrem = __ballot(s >= 0);
    int cnt = __popcll(mrem);                       // uniform

    int J0 = 0, J1 = 0, J2 = 0, J3 = 0;
    float c0 = 0.f, c1 = 0.f, c2 = 0.f, c3 = 0.f;
    if (cnt >= 4) {                                 // prologue: prefetch g1
        J0 = __ffsll((long long)mrem) - 1; mrem &= mrem - 1;
        J1 = __ffsll((long long)mrem) - 1; mrem &= mrem - 1;
        J2 = __ffsll((long long)mrem) - 1; mrem &= mrem - 1;
        J3 = __ffsll((long long)mrem) - 1; mrem &= mrem - 1;
        c0 = values[(size_t)(p0 + J0) * NIN + lane];   // coalesced 256B
        c1 = values[(size_t)(p0 + J1) * NIN + lane];
        c2 = values[(size_t)(p0 + J2) * NIN + lane];
        c3 = values[(size_t)(p0 + J3) * NIN + lane];
    }
    int pc = 0;
    while (cnt >= 4) {
        cnt -= 4;
        // Current group's slots (captured before the prefetch pops).
        const int s0 = __shfl(s, J0);
        const int s1 = __shfl(s, J1);
        const int s2 = __shfl(s, J2);
        const int s3 = __shfl(s, J3);
        // Scalar-pipe row pointers for the CURRENT group (uniform -> SGPR).
        const float* sp0 = values + (size_t)__builtin_amdgcn_readfirstlane(p0 + J0) * NIN;
        const float* sp1 = values + (size_t)__builtin_amdgcn_readfirstlane(p0 + J1) * NIN;
        const float* sp2 = values + (size_t)__builtin_amdgcn_readfirstlane(p0 + J2) * NIN;
        const float* sp3 = values + (size_t)__builtin_amdgcn_readfirstlane(p0 + J3) * NIN;
        // Issue scalar loads of els 48..63 now; used at the END of the fmac
        // block (~130 cyc away) so the SQC miss hides under LDS fmacs.
        float h0[16], h1[16], h2[16], h3[16];
#pragma unroll
        for (int i = 0; i < 16; ++i) h0[i] = sp0[48 + i];
#pragma unroll
        for (int i = 0; i < 16; ++i) h1[i] = sp1[48 + i];
#pragma unroll
        for (int i = 0; i < 16; ++i) h2[i] = sp2[48 + i];
#pragma unroll
        for (int i = 0; i < 16; ++i) h3[i] = sp3[48 + i];
        // Stage current rows to LDS (waits vmcnt for the vector loads).
        float* rw = &rows[wv][pc][0][0];
        rw[0 * NIN + lane] = c0;
        rw[1 * NIN + lane] = c1;
        rw[2 * NIN + lane] = c2;
        rw[3 * NIN + lane] = c3;
        // Prefetch next group's rows (latency hides under fmacs below).
        float n0 = 0.f, n1 = 0.f, n2 = 0.f, n3 = 0.f;
        if (cnt >= 4) {
            J0 = __ffsll((long long)mrem) - 1; mrem &= mrem - 1;
            J1 = __ffsll((long long)mrem) - 1; mrem &= mrem - 1;
            J2 = __ffsll((long long)mrem) - 1; mrem &= mrem - 1;
            J3 = __ffsll((long long)mrem) - 1; mrem &= mrem - 1;
            n0 = values[(size_t)(p0 + J0) * NIN + lane];
            n1 = values[(size_t)(p0 + J1) * NIN + lane];
            n2 = values[(size_t)(p0 + J2) * NIN + lane];
            n3 = values[(size_t)(p0 + J3) * NIN + lane];
        }
        // Els 0..47 via broadcast ds_read_b128 (12 reads/row), 4 chains.
        const float4* q0 = reinterpret_cast<const float4*>(rw + 0 * NIN);
        const float4* q1 = reinterpret_cast<const float4*>(rw + 1 * NIN);
        const float4* q2 = reinterpret_cast<const float4*>(rw + 2 * NIN);
        const float4* q3 = reinterpret_cast<const float4*>(rw + 3 * NIN);
        float a0 = 0.f, a1 = 0.f, a2 = 0.f, a3 = 0.f;
#pragma unroll
        for (int i4 = 0; i4 < 12; ++i4) {
            const float4 w0 = q0[i4];
            const float4 w1 = q1[i4];
            const float4 w2 = q2[i4];
            const float4 w3 = q3[i4];
            a0 = fmaf(w0.x, kreg[4 * i4 + 0], a0);
            a0 = fmaf(w0.y, kreg[4 * i4 + 1], a0);
            a0 = fmaf(w0.z, kreg[4 * i4 + 2], a0);
            a0 = fmaf(w0.w, kreg[4 * i4 + 3], a0);
            a1 = fmaf(w1.x, kreg[4 * i4 + 0], a1);
            a1 = fmaf(w1.y, kreg[4 * i4 + 1], a1);
            a1 = fmaf(w1.z, kreg[4 * i4 + 2], a1);
            a1 = fmaf(w1.w, kreg[4 * i4 + 3], a1);
            a2 = fmaf(w2.x, kreg[4 * i4 + 0], a2);
            a2 = fmaf(w2.y, kreg[4 * i4 + 1], a2);
            a2 = fmaf(w2.z, kreg[4 * i4 + 2], a2);
            a2 = fmaf(w2.w, kreg[4 * i4 + 3], a2);
            a3 = fmaf(w3.x, kreg[4 * i4 + 0], a3);
            a3 = fmaf(w3.y, kreg[4 * i4 + 1], a3);
            a3 = fmaf(w3.z, kreg[4 * i4 + 2], a3);
            a3 = fmaf(w3.w, kreg[4 * i4 + 3], a3);
        }
        // Els 48..63 via the scalar pipe (SGPR operand of v_fmac).
#pragma unroll
        for (int i = 0; i < 16; ++i) {
            a0 = fmaf(h0[i], kreg[48 + i], a0);
            a1 = fmaf(h1[i], kreg[48 + i], a1);
            a2 = fmaf(h2[i], kreg[48 + i], a2);
            a3 = fmaf(h3[i], kreg[48 + i], a3);
        }
        atomicAdd(&compact[(size_t)s0 * NOUT + lane], a0);
        atomicAdd(&compact[(size_t)s1 * NOUT + lane], a1);
        atomicAdd(&compact[(size_t)s2 * NOUT + lane], a2);
        atomicAdd(&compact[(size_t)s3 * NOUT + lane], a3);
        c0 = n0; c1 = n1; c2 = n2; c3 = n3;     // rotate prefetched rows
        pc ^= 1;
    }
    // Remainder (<=3 dots): simple path.
    while (mrem) {
        const int j = __ffsll((long long)mrem) - 1; mrem &= mrem - 1;
        const int sj = __shfl(s, j);
        const float* vp = values + (size_t)(p0 + j) * NIN;
        float a = 0.f;
#pragma unroll
        for (int i = 0; i < NIN; ++i) a = fmaf(vp[i], kreg[i], a);
        atomicAdd(&compact[(size_t)sj * NOUT + lane], a);
    }
}

// ---------------------------------------------------------------------------
// Streaming finalize: writes EVERY output element exactly once.
//   dead pixel  -> 0 ; alive -> (compact[slot] + m*bias) * m
// ---------------------------------------------------------------------------
__global__ void finalize2_kernel(float* __restrict__ out,
                                 const float* __restrict__ mask,
                                 const int* __restrict__ slot,
                                 const float* __restrict__ compact,
                                 const float* __restrict__ bias) {
    const int t = blockIdx.x * blockDim.x + threadIdx.x;
    const int p = t >> 4;
    const int c4 = (t & 15) * 4;
    if (p >= NPIX) return;
    float4* o = reinterpret_cast<float4*>(out + (size_t)p * NOUT + c4);
    const int s = slot[p];
    if (s < 0) {
        *o = make_float4(0.f, 0.f, 0.f, 0.f);
        return;
    }
    const float m = mask[p];
    const float4 bb = *reinterpret_cast<const float4*>(bias + c4);
    float4 v = *reinterpret_cast<const float4*>(compact + (size_t)s * NOUT + c4);
    v.x = (v.x + m * bb.x) * m;
    v.y = (v.y + m * bb.y) * m;
    v.z = (v.z + m * bb.z) * m;
    v.w = (v.w + m * bb.w) * m;
    *o = v;
}

// ======================= Fallback path (R3, proven) ========================
__global__ __launch_bounds__(64, 2) void conv_scatter_kernel(
        const float* __restrict__ values,
        const float* __restrict__ kern,
        const int* __restrict__ idx,
        const float* __restrict__ mask,
        float* __restrict__ dense) {
    const int bid  = blockIdx.x;
    const int tap  = bid % 9;
    const int tile = bid / 9;
    const int lane = threadIdx.x;
    const int ky = tap / 3;
    const int kx = tap % 3;
    float kreg[NIN];
    const float* kp = kern + (size_t)tap * NIN * NOUT + lane;
#pragma unroll
    for (int i = 0; i < NIN; ++i) kreg[i] = kp[(size_t)i * NOUT];
#pragma unroll
    for (int i = 0; i < NIN; ++i) asm volatile("" : "+v"(kreg[i]));
    const int p0 = tile * PPW;
    for (int pp = 0; pp < PPW; ++pp) {
        const int p = p0 + pp;
        const int b = idx[p * 3 + 0];
        const int y = idx[p * 3 + 1];
        const int x = idx[p * 3 + 2];
        const int sy = min(max(y + ky - 1, 0), HH - 1);
        const int sx = min(max(x + kx - 1, 0), WW - 1);
        const size_t pix = ((size_t)b * HH + sy) * WW + sx;
        if (mask[pix] != 0.0f) {
            const float* vp = values + (size_t)p * NIN;
            float acc = 0.0f;
#pragma unroll
            for (int i = 0; i < NIN; ++i) acc = fmaf(vp[i], kreg[i], acc);
            atomicAdd(&dense[pix * NOUT + lane], acc);
        }
    }
}

__global__ void finalize_kernel(float* __restrict__ out,
                                const float* __restrict__ mask,
                                const float* __restrict__ bias) {
    const int t = blockIdx.x * blockDim.x + threadIdx.x;
    const int p = t >> 4;
    const int c4 = (t & 15) * 4;
    if (p >= NPIX) return;
    const float m = mask[p];
    if (m == 0.0f) return;
    float4* o = reinterpret_cast<float4*>(out + (size_t)p * NOUT + c4);
    const float4 bb = *reinterpret_cast<const float4*>(bias + c4);
    float4 v = *o;
    v.x = (v.x + m * bb.x) * m;
    v.y = (v.y + m * bb.y) * m;
    v.z = (v.z + m * bb.z) * m;
    v.w = (v.w + m * bb.w) * m;
    *o = v;
}

extern "C" void kernel_launch(void* const* d_in, const int* in_sizes, int n_in,
                              void* d_out, int out_size, void* d_ws, size_t ws_size,
                              hipStream_t stream) {
    const float* values      = (const float*)d_in[0];
    const float* kern        = (const float*)d_in[1];
    const float* bias        = (const float*)d_in[2];
    const float* mask_values = (const float*)d_in[3];
    const int*   indices     = (const int*)d_in[4];
    const int*   mask_idx    = (const int*)d_in[5];
    float* out = (float*)d_out;

    if (ws_size >= WS_NEED) {
        // ---- compact path ----
        char* ws = (char*)d_ws;
        int*   counter = (int*)ws;
        float* mask    = (float*)(ws + WS_MASK_OFF);
        float* compact = (float*)(ws + WS_CMP_OFF);
        int*   slot    = (int*)(ws + WS_SLOT_OFF);

        hipMemsetAsync(ws, 0, WS_MEMSET, stream);  // counter+mask+compact

        mask_scatter_kernel<<<(N_MASK + 255) / 256, 256, 0, stream>>>(
            mask_values, mask_idx, mask);
        build_slot2_kernel<<<NPIX / 4 / 256, 256, 0, stream>>>(
            mask, slot, counter);

        const int nwaves = 9 * (N_NZ / PPW);        // 18432
        conv_scatter7_kernel<<<nwaves / 4, 256, 0, stream>>>(
            values, kern, indices, slot, compact);

        const int total = NPIX * (NOUT / 4);
        finalize2_kernel<<<(total + 255) / 256, 256, 0, stream>>>(
            out, mask, slot, compact, bias);
    } else {
        // ---- fallback: R3 structure ----
        float* mask = (float*)d_ws;
        hipMemsetAsync(out, 0, (size_t)out_size * sizeof(float), stream);
        hipMemsetAsync(mask, 0, (size_t)NPIX * sizeof(float), stream);
        mask_scatter_kernel<<<(N_MASK + 255) / 256, 256, 0, stream>>>(
            mask_values, mask_idx, mask);
        const int nblocks = 9 * (N_NZ / PPW);
        conv_scatter_kernel<<<nblocks, 64, 0, stream>>>(
            values, kern, indices, mask, out);
        const int total = NPIX * (NOUT / 4);
        finalize_kernel<<<(total + 255) / 256, 256, 0, stream>>>(out, mask, bias);
    }
}

// Round 10
// 250.676 us; speedup vs baseline: 1.5594x; 1.0046x over previous
//
#include <hip/hip_runtime.h>

// Problem constants (from reference)
#define BATCH 2
#define HH 512
#define WW 512
#define NIN 64
#define NOUT 64
#define N_NZ 131072
#define N_MASK 131072
#define NPIX (BATCH * HH * WW)   // 524288
#define PPW 64                   // points per wave in conv kernel
#define MAX_ALIVE N_MASK         // alive pixels <= number of mask points

// d_ws layout (compact path).
//   [0,256)            int counter
//   [256, +2MB)        float mask[NPIX]
//   [.., +32MB)        float compact[MAX_ALIVE*NOUT]   (zeroed by build_slot3)
//   [.., +2MB)         int   slot[NPIX]                (fully overwritten)
// R13: memset covers ONLY {counter, mask} (2.1MB); compact zeroing folded
// into build_slot3 (kernel boundary orders it before conv's atomics).
#define WS_MASK_OFF   256
#define WS_CMP_OFF    (WS_MASK_OFF + (size_t)NPIX * 4)
#define WS_SLOT_OFF   (WS_CMP_OFF + (size_t)MAX_ALIVE * NOUT * 4)
#define WS_NEED       (WS_SLOT_OFF + (size_t)NPIX * 4)
#define WS_MEMSET     WS_CMP_OFF

// ---------------------------------------------------------------------------
// Mask scatter:  mask[b,y,x] += mask_values[n]
// ---------------------------------------------------------------------------
__global__ void mask_scatter_kernel(const float* __restrict__ mv,
                                    const int* __restrict__ midx,
                                    float* __restrict__ mask) {
    int n = blockIdx.x * blockDim.x + threadIdx.x;
    if (n < N_MASK) {
        int b = midx[n * 3 + 0];
        int y = midx[n * 3 + 1];
        int x = midx[n * 3 + 2];
        atomicAdd(&mask[(b * HH + y) * WW + x], mv[n]);
    }
}

// ---------------------------------------------------------------------------
// Slot assignment (v3): block-aggregated scan, ONE counter atomic per block,
// PLUS grid-stride zeroing of compact (replaces 33.5MB of the memset node).
// ---------------------------------------------------------------------------
__global__ __launch_bounds__(256) void build_slot3_kernel(
        const float* __restrict__ mask,
        int* __restrict__ slot,
        int* __restrict__ counter,
        float4* __restrict__ compactz) {
    // Zero compact: 512 blocks x 256 threads, 16 float4/thread.
    const int ztot = MAX_ALIVE * NOUT / 4;
    const float4 z4 = make_float4(0.f, 0.f, 0.f, 0.f);
    for (int z = blockIdx.x * 256 + threadIdx.x; z < ztot; z += 512 * 256)
        compactz[z] = z4;

    const int tid = threadIdx.x;
    const int gid = blockIdx.x * 256 + tid;     // over NPIX/4 groups
    const float4 m = reinterpret_cast<const float4*>(mask)[gid];
    const int c0 = (m.x != 0.f) + (m.y != 0.f) + (m.z != 0.f) + (m.w != 0.f);

    const int lane = tid & 63;
    const int wv = tid >> 6;
    int pre = c0;
#pragma unroll
    for (int d = 1; d < 64; d <<= 1) {
        int t = __shfl_up(pre, d);
        if (lane >= d) pre += t;
    }

    __shared__ int wsum[4];
    __shared__ int wbase[4];
    __shared__ int blockbase;
    if (lane == 63) wsum[wv] = pre;
    __syncthreads();
    if (tid == 0) {
        int s = 0;
#pragma unroll
        for (int w = 0; w < 4; ++w) { wbase[w] = s; s += wsum[w]; }
        blockbase = atomicAdd(counter, s);      // ONE atomic per block
    }
    __syncthreads();

    int s0 = blockbase + wbase[wv] + (pre - c0);  // exclusive prefix
    int4 sv;
    sv.x = (m.x != 0.f) ? s0++ : -1;
    sv.y = (m.y != 0.f) ? s0++ : -1;
    sv.z = (m.z != 0.f) ? s0++ : -1;
    sv.w = (m.w != 0.f) ? s0++ : -1;
    reinterpret_cast<int4*>(slot)[gid] = sv;
}

// ---------------------------------------------------------------------------
// Conv scatter v6 (REVERTED to the R11-measured 80us version; v7's LDS+scalar
// hybrid regressed to 85us: s_load and ds_read share lgkmcnt, so the waits
// serialize the two pipes, and SQC line throughput (~132cyc) can't carry 16
// els/dot concurrently).  v6 model, confirmed by counters: 17 LDS instrs/dot
// x ~11.5cyc on the per-CU LDS unit = 192cyc/dot -> 80us.  Beating this
// requires fewer LDS bytes/instrs (bf16 rows: accuracy risk) or MFMA
// (operand reuse in the matrix engine) — future round.
// ---------------------------------------------------------------------------
__global__ __launch_bounds__(256, 2) void conv_scatter6_kernel(
        const float* __restrict__ values,   // (N_NZ, NIN)
        const float* __restrict__ kern,     // (3,3,NIN,NOUT)
        const int* __restrict__ idx,        // (N_NZ,3) int32
        const int* __restrict__ slot,       // (NPIX,) slot id or -1
        float* __restrict__ compact) {      // (MAX_ALIVE, NOUT) zeroed
    const int wv   = threadIdx.x >> 6;              // wave in block
    const int wg   = blockIdx.x * 4 + wv;           // global wave id
    const int tap  = wg % 9;                        // 9 taps of a tile adjacent
    const int tile = wg / 9;                        // -> values rows L2-hot
    const int lane = threadIdx.x & 63;
    const int ky = tap / 3;
    const int kx = tap % 3;

    // Wave-private row staging: [wave][parity][chain][elem] = 8KB/block.
    __shared__ __align__(16) float rows[4][2][4][NIN];

    // This tap's 64x64 kernel slice -> 64 regs (lane = output channel).
    float kreg[NIN];
    const float* kp = kern + (size_t)tap * NIN * NOUT + lane;
#pragma unroll
    for (int i = 0; i < NIN; ++i) kreg[i] = kp[(size_t)i * NOUT];
    // Pin: forbid rematerialization (R5 evidence: remat re-read 16KB/wave).
#pragma unroll
    for (int i = 0; i < NIN; ++i) asm volatile("" : "+v"(kreg[i]));

    // Lane-parallel probe of 64 points' destinations.
    const int p0 = tile * PPW;
    const int p  = p0 + lane;
    const int b = idx[p * 3 + 0];
    const int y = idx[p * 3 + 1];
    const int x = idx[p * 3 + 2];
    const int sy = min(max(y + ky - 1, 0), HH - 1);
    const int sx = min(max(x + kx - 1, 0), WW - 1);
    const int pix = (b * HH + sy) * WW + sx;
    const int s = slot[pix];

    unsigned long long mrem = __ballot(s >= 0);
    int cnt = __popcll(mrem);                       // uniform

    int J0 = 0, J1 = 0, J2 = 0, J3 = 0;
    float c0 = 0.f, c1 = 0.f, c2 = 0.f, c3 = 0.f;
    if (cnt >= 4) {                                 // prologue: prefetch g1
        J0 = __ffsll((long long)mrem) - 1; mrem &= mrem - 1;
        J1 = __ffsll((long long)mrem) - 1; mrem &= mrem - 1;
        J2 = __ffsll((long long)mrem) - 1; mrem &= mrem - 1;
        J3 = __ffsll((long long)mrem) - 1; mrem &= mrem - 1;
        c0 = values[(size_t)(p0 + J0) * NIN + lane];   // coalesced 256B
        c1 = values[(size_t)(p0 + J1) * NIN + lane];
        c2 = values[(size_t)(p0 + J2) * NIN + lane];
        c3 = values[(size_t)(p0 + J3) * NIN + lane];
    }
    int pc = 0;
    while (cnt >= 4) {
        cnt -= 4;
        // Current group's slots (J* captured before the prefetch pops).
        const int s0 = __shfl(s, J0);
        const int s1 = __shfl(s, J1);
        const int s2 = __shfl(s, J2);
        const int s3 = __shfl(s, J3);
        // Stage current rows to LDS (waits vmcnt for the loads).
        float* rw = &rows[wv][pc][0][0];
        rw[0 * NIN + lane] = c0;
        rw[1 * NIN + lane] = c1;
        rw[2 * NIN + lane] = c2;
        rw[3 * NIN + lane] = c3;
        // Prefetch next group's rows (latency hides under fmacs below).
        float n0 = 0.f, n1 = 0.f, n2 = 0.f, n3 = 0.f;
        if (cnt >= 4) {
            J0 = __ffsll((long long)mrem) - 1; mrem &= mrem - 1;
            J1 = __ffsll((long long)mrem) - 1; mrem &= mrem - 1;
            J2 = __ffsll((long long)mrem) - 1; mrem &= mrem - 1;
            J3 = __ffsll((long long)mrem) - 1; mrem &= mrem - 1;
            n0 = values[(size_t)(p0 + J0) * NIN + lane];
            n1 = values[(size_t)(p0 + J1) * NIN + lane];
            n2 = values[(size_t)(p0 + J2) * NIN + lane];
            n3 = values[(size_t)(p0 + J3) * NIN + lane];
        }
        // Broadcast ds_read_b128 (uniform addr, conflict-free) + 4 chains.
        const float4* q0 = reinterpret_cast<const float4*>(rw + 0 * NIN);
        const float4* q1 = reinterpret_cast<const float4*>(rw + 1 * NIN);
        const float4* q2 = reinterpret_cast<const float4*>(rw + 2 * NIN);
        const float4* q3 = reinterpret_cast<const float4*>(rw + 3 * NIN);
        float a0 = 0.f, a1 = 0.f, a2 = 0.f, a3 = 0.f;
#pragma unroll
        for (int i4 = 0; i4 < 16; ++i4) {
            const float4 w0 = q0[i4];
            const float4 w1 = q1[i4];
            const float4 w2 = q2[i4];
            const float4 w3 = q3[i4];
            a0 = fmaf(w0.x, kreg[4 * i4 + 0], a0);
            a0 = fmaf(w0.y, kreg[4 * i4 + 1], a0);
            a0 = fmaf(w0.z, kreg[4 * i4 + 2], a0);
            a0 = fmaf(w0.w, kreg[4 * i4 + 3], a0);
            a1 = fmaf(w1.x, kreg[4 * i4 + 0], a1);
            a1 = fmaf(w1.y, kreg[4 * i4 + 1], a1);
            a1 = fmaf(w1.z, kreg[4 * i4 + 2], a1);
            a1 = fmaf(w1.w, kreg[4 * i4 + 3], a1);
            a2 = fmaf(w2.x, kreg[4 * i4 + 0], a2);
            a2 = fmaf(w2.y, kreg[4 * i4 + 1], a2);
            a2 = fmaf(w2.z, kreg[4 * i4 + 2], a2);
            a2 = fmaf(w2.w, kreg[4 * i4 + 3], a2);
            a3 = fmaf(w3.x, kreg[4 * i4 + 0], a3);
            a3 = fmaf(w3.y, kreg[4 * i4 + 1], a3);
            a3 = fmaf(w3.z, kreg[4 * i4 + 2], a3);
            a3 = fmaf(w3.w, kreg[4 * i4 + 3], a3);
        }
        atomicAdd(&compact[(size_t)s0 * NOUT + lane], a0);
        atomicAdd(&compact[(size_t)s1 * NOUT + lane], a1);
        atomicAdd(&compact[(size_t)s2 * NOUT + lane], a2);
        atomicAdd(&compact[(size_t)s3 * NOUT + lane], a3);
        c0 = n0; c1 = n1; c2 = n2; c3 = n3;     // rotate prefetched rows
        pc ^= 1;
    }
    // Remainder (<=3 dots): simple path.
    while (mrem) {
        const int j = __ffsll((long long)mrem) - 1; mrem &= mrem - 1;
        const int sj = __shfl(s, j);
        const float* vp = values + (size_t)(p0 + j) * NIN;
        float a = 0.f;
#pragma unroll
        for (int i = 0; i < NIN; ++i) a = fmaf(vp[i], kreg[i], a);
        atomicAdd(&compact[(size_t)sj * NOUT + lane], a);
    }
}

// ---------------------------------------------------------------------------
// Streaming finalize: writes EVERY output element exactly once.
//   dead pixel  -> 0 ; alive -> (compact[slot] + m*bias) * m
// ---------------------------------------------------------------------------
__global__ void finalize2_kernel(float* __restrict__ out,
                                 const float* __restrict__ mask,
                                 const int* __restrict__ slot,
                                 const float* __restrict__ compact,
                                 const float* __restrict__ bias) {
    const int t = blockIdx.x * blockDim.x + threadIdx.x;
    const int p = t >> 4;
    const int c4 = (t & 15) * 4;
    if (p >= NPIX) return;
    float4* o = reinterpret_cast<float4*>(out + (size_t)p * NOUT + c4);
    const int s = slot[p];
    if (s < 0) {
        *o = make_float4(0.f, 0.f, 0.f, 0.f);
        return;
    }
    const float m = mask[p];
    const float4 bb = *reinterpret_cast<const float4*>(bias + c4);
    float4 v = *reinterpret_cast<const float4*>(compact + (size_t)s * NOUT + c4);
    v.x = (v.x + m * bb.x) * m;
    v.y = (v.y + m * bb.y) * m;
    v.z = (v.z + m * bb.z) * m;
    v.w = (v.w + m * bb.w) * m;
    *o = v;
}

// ======================= Fallback path (R3, proven) ========================
__global__ __launch_bounds__(64, 2) void conv_scatter_kernel(
        const float* __restrict__ values,
        const float* __restrict__ kern,
        const int* __restrict__ idx,
        const float* __restrict__ mask,
        float* __restrict__ dense) {
    const int bid  = blockIdx.x;
    const int tap  = bid % 9;
    const int tile = bid / 9;
    const int lane = threadIdx.x;
    const int ky = tap / 3;
    const int kx = tap % 3;
    float kreg[NIN];
    const float* kp = kern + (size_t)tap * NIN * NOUT + lane;
#pragma unroll
    for (int i = 0; i < NIN; ++i) kreg[i] = kp[(size_t)i * NOUT];
#pragma unroll
    for (int i = 0; i < NIN; ++i) asm volatile("" : "+v"(kreg[i]));
    const int p0 = tile * PPW;
    for (int pp = 0; pp < PPW; ++pp) {
        const int p = p0 + pp;
        const int b = idx[p * 3 + 0];
        const int y = idx[p * 3 + 1];
        const int x = idx[p * 3 + 2];
        const int sy = min(max(y + ky - 1, 0), HH - 1);
        const int sx = min(max(x + kx - 1, 0), WW - 1);
        const size_t pix = ((size_t)b * HH + sy) * WW + sx;
        if (mask[pix] != 0.0f) {
            const float* vp = values + (size_t)p * NIN;
            float acc = 0.0f;
#pragma unroll
            for (int i = 0; i < NIN; ++i) acc = fmaf(vp[i], kreg[i], acc);
            atomicAdd(&dense[pix * NOUT + lane], acc);
        }
    }
}

__global__ void finalize_kernel(float* __restrict__ out,
                                const float* __restrict__ mask,
                                const float* __restrict__ bias) {
    const int t = blockIdx.x * blockDim.x + threadIdx.x;
    const int p = t >> 4;
    const int c4 = (t & 15) * 4;
    if (p >= NPIX) return;
    const float m = mask[p];
    if (m == 0.0f) return;
    float4* o = reinterpret_cast<float4*>(out + (size_t)p * NOUT + c4);
    const float4 bb = *reinterpret_cast<const float4*>(bias + c4);
    float4 v = *o;
    v.x = (v.x + m * bb.x) * m;
    v.y = (v.y + m * bb.y) * m;
    v.z = (v.z + m * bb.z) * m;
    v.w = (v.w + m * bb.w) * m;
    *o = v;
}

extern "C" void kernel_launch(void* const* d_in, const int* in_sizes, int n_in,
                              void* d_out, int out_size, void* d_ws, size_t ws_size,
                              hipStream_t stream) {
    const float* values      = (const float*)d_in[0];
    const float* kern        = (const float*)d_in[1];
    const float* bias        = (const float*)d_in[2];
    const float* mask_values = (const float*)d_in[3];
    const int*   indices     = (const int*)d_in[4];
    const int*   mask_idx    = (const int*)d_in[5];
    float* out = (float*)d_out;

    if (ws_size >= WS_NEED) {
        // ---- compact path ----
        char* ws = (char*)d_ws;
        int*   counter = (int*)ws;
        float* mask    = (float*)(ws + WS_MASK_OFF);
        float* compact = (float*)(ws + WS_CMP_OFF);
        int*   slot    = (int*)(ws + WS_SLOT_OFF);

        hipMemsetAsync(ws, 0, WS_MEMSET, stream);  // counter+mask ONLY (2.1MB)

        mask_scatter_kernel<<<(N_MASK + 255) / 256, 256, 0, stream>>>(
            mask_values, mask_idx, mask);
        build_slot3_kernel<<<NPIX / 4 / 256, 256, 0, stream>>>(
            mask, slot, counter, (float4*)compact);

        const int nwaves = 9 * (N_NZ / PPW);        // 18432
        conv_scatter6_kernel<<<nwaves / 4, 256, 0, stream>>>(
            values, kern, indices, slot, compact);

        const int total = NPIX * (NOUT / 4);
        finalize2_kernel<<<(total + 255) / 256, 256, 0, stream>>>(
            out, mask, slot, compact, bias);
    } else {
        // ---- fallback: R3 structure ----
        float* mask = (float*)d_ws;
        hipMemsetAsync(out, 0, (size_t)out_size * sizeof(float), stream);
        hipMemsetAsync(mask, 0, (size_t)NPIX * sizeof(float), stream);
        mask_scatter_kernel<<<(N_MASK + 255) / 256, 256, 0, stream>>>(
            mask_values, mask_idx, mask);
        const int nblocks = 9 * (N_NZ / PPW);
        conv_scatter_kernel<<<nblocks, 64, 0, stream>>>(
            values, kern, indices, mask, out);
        const int total = NPIX * (NOUT / 4);
        finalize_kernel<<<(total + 255) / 256, 256, 0, stream>>>(out, mask, bias);
    }
}